// Round 3
// baseline (491.411 us; speedup 1.0000x reference)
//
#include <hip/hip_runtime.h>
#include <stdint.h>

typedef uint32_t u32;
typedef uint16_t u16;

static constexpr int M_DIM = 8192;
static constexpr int N_DIM = 1024;
static constexpr int K_DIM = 4096;
static constexpr int BM = 128;
static constexpr int BN = 128;
static constexpr int BK = 32;
static constexpr int K_TILES = K_DIM / BK;   // 128
static constexpr int A_STRIDE = 40;          // fp16 elems per A row: 32 + 8 pad -> 80 B rows

typedef __attribute__((ext_vector_type(8))) _Float16 half8;  // MFMA A/B frag (4 VGPRs)
typedef __attribute__((ext_vector_type(4))) float f32x4;     // MFMA C/D frag

__device__ __forceinline__ u32 pack2(float a, float b) {
  union { _Float16 h[2]; u32 u; } p;
  p.h[0] = (_Float16)a;   // v_cvt_f16_f32, RNE
  p.h[1] = (_Float16)b;
  return p.u;
}

// GELU via Abramowitz-Stegun 7.1.26 erf (|err| <= 1.5e-7) — near-exact vs erf reference.
// gelu(x) = 0.5 * x * (1 + erf(x/sqrt(2)))
__device__ __forceinline__ float gelu_drop(float x, u32 keep) {
  float ax = fabsf(x);
  float z  = ax * 0.70710678f;
  float t  = __builtin_amdgcn_rcpf(fmaf(0.3275911f, z, 1.0f));
  float poly = fmaf(fmaf(fmaf(fmaf(1.061405429f, t, -1.453152027f),
                              t, 1.421413741f),
                         t, -0.284496736f),
                    t, 0.254829592f) * t;
  float e   = exp2f(z * z * -1.44269504f);    // exp(-z^2)
  float erf = fmaf(-poly, e, 1.0f);           // erf(|x|/sqrt(2)) in [0,1)
  float g   = 0.5f * x * (1.0f + copysignf(erf, x));
  return keep ? g * 1.1111112f : 0.0f;        // dropout keep-mask * 1/(1-0.1)
}

__global__ __launch_bounds__(256, 2)
void fused_gelu_dropout_linear_kernel(const float* __restrict__ X,
                                      const float* __restrict__ W,
                                      const float* __restrict__ Bias,
                                      const int* __restrict__ Mask,
                                      float* __restrict__ Out) {
  __shared__ __attribute__((aligned(16))) _Float16 As[BM * A_STRIDE];  // 10240 B
  __shared__ __attribute__((aligned(16))) _Float16 Bs[BN * BK];        // 8192 B

  const int tid  = threadIdx.x;
  const int lane = tid & 63;
  const int wv   = tid >> 6;
  const int wr   = wv >> 1;   // wave row 0..1 (64-row half of the 128x128 tile)
  const int wc   = wv & 1;    // wave col 0..1

  // m-fast block order: the 8 n-blocks of one row-stripe land on one XCD (%8),
  // so the 8x re-reads of x/mask hit that XCD's L2 instead of HBM.
  const int bm = blockIdx.x & 63;
  const int bn = blockIdx.x >> 6;
  const int m0 = bm * BM;
  const int n0 = bn * BN;

  // ---- A staging: each thread transforms 16 contiguous k of one row ----
  const int a_m = tid >> 1;           // 0..127
  const int a_k = (tid & 1) << 4;     // 0 or 16
  const float* xptr = X    + (size_t)(m0 + a_m) * K_DIM + a_k;
  const int*   mptr = Mask + (size_t)(m0 + a_m) * K_DIM + a_k;
  _Float16* a_lds = &As[a_m * A_STRIDE + a_k];

  // ---- B staging: thread i covers (row = i>>2, k8 = (i&3)*8), i in {tid, tid+256} ----
  const int i0 = tid, i1 = tid + 256;
  const float* wp0 = W + (size_t)(n0 + (i0 >> 2)) * K_DIM + ((i0 & 3) << 3);
  const float* wp1 = W + (size_t)(n0 + (i1 >> 2)) * K_DIM + ((i1 & 3) << 3);
  _Float16* bl0 = &Bs[i0 * 8];
  _Float16* bl1 = &Bs[i1 * 8];

  f32x4 acc[4][4];
#pragma unroll
  for (int i = 0; i < 4; ++i)
#pragma unroll
    for (int j = 0; j < 4; ++j)
      acc[i][j] = (f32x4){0.f, 0.f, 0.f, 0.f};

  // prefetch k-tile 0 into registers
  float4 xf0 = *(const float4*)(xptr +  0);
  float4 xf1 = *(const float4*)(xptr +  4);
  float4 xf2 = *(const float4*)(xptr +  8);
  float4 xf3 = *(const float4*)(xptr + 12);
  uint4  mr0 = *(const uint4*)(mptr +  0);
  uint4  mr1 = *(const uint4*)(mptr +  4);
  uint4  mr2 = *(const uint4*)(mptr +  8);
  uint4  mr3 = *(const uint4*)(mptr + 12);
  float4 wf0 = *(const float4*)(wp0 + 0);
  float4 wf1 = *(const float4*)(wp0 + 4);
  float4 wf2 = *(const float4*)(wp1 + 0);
  float4 wf3 = *(const float4*)(wp1 + 4);

#pragma unroll 1
  for (int kt = 0; kt < K_TILES; ++kt) {
    // ---- transform current regs -> A LDS (GELU * mask * scale, cvt fp16) ----
    {
      float xs[16] = {xf0.x, xf0.y, xf0.z, xf0.w, xf1.x, xf1.y, xf1.z, xf1.w,
                      xf2.x, xf2.y, xf2.z, xf2.w, xf3.x, xf3.y, xf3.z, xf3.w};
      u32 mk[16]   = {mr0.x, mr0.y, mr0.z, mr0.w, mr1.x, mr1.y, mr1.z, mr1.w,
                      mr2.x, mr2.y, mr2.z, mr2.w, mr3.x, mr3.y, mr3.z, mr3.w};
      u32 ow[8];
#pragma unroll
      for (int e = 0; e < 8; ++e) {
        float h0 = gelu_drop(xs[2 * e],     mk[2 * e]);
        float h1 = gelu_drop(xs[2 * e + 1], mk[2 * e + 1]);
        ow[e] = pack2(h0, h1);
      }
      ((uint4*)a_lds)[0] = make_uint4(ow[0], ow[1], ow[2], ow[3]);
      ((uint4*)a_lds)[1] = make_uint4(ow[4], ow[5], ow[6], ow[7]);
    }
    // ---- W f32 regs -> fp16 -> LDS ----
    {
      u32 b0 = pack2(wf0.x, wf0.y), b1 = pack2(wf0.z, wf0.w);
      u32 b2 = pack2(wf1.x, wf1.y), b3 = pack2(wf1.z, wf1.w);
      u32 b4 = pack2(wf2.x, wf2.y), b5 = pack2(wf2.z, wf2.w);
      u32 b6 = pack2(wf3.x, wf3.y), b7 = pack2(wf3.z, wf3.w);
      *(uint4*)bl0 = make_uint4(b0, b1, b2, b3);
      *(uint4*)bl1 = make_uint4(b4, b5, b6, b7);
    }
    __syncthreads();

    // ---- prefetch next k-tile while MFMA phase runs ----
    if (kt + 1 < K_TILES) {
      xptr += BK; mptr += BK; wp0 += BK; wp1 += BK;
      xf0 = *(const float4*)(xptr +  0);
      xf1 = *(const float4*)(xptr +  4);
      xf2 = *(const float4*)(xptr +  8);
      xf3 = *(const float4*)(xptr + 12);
      mr0 = *(const uint4*)(mptr +  0);
      mr1 = *(const uint4*)(mptr +  4);
      mr2 = *(const uint4*)(mptr +  8);
      mr3 = *(const uint4*)(mptr + 12);
      wf0 = *(const float4*)(wp0 + 0);
      wf1 = *(const float4*)(wp0 + 4);
      wf2 = *(const float4*)(wp1 + 0);
      wf3 = *(const float4*)(wp1 + 4);
    }

    // ---- MFMA: 4x4 of 16x16x32 f16 per wave ----
    {
      const int fr = lane & 15;
      const int fk = (lane >> 4) << 3;   // k-chunk 0/8/16/24
      half8 ar[4], br[4];
#pragma unroll
      for (int i = 0; i < 4; ++i)
        ar[i] = *(const half8*)&As[(wr * 64 + i * 16 + fr) * A_STRIDE + fk];
#pragma unroll
      for (int j = 0; j < 4; ++j)
        br[j] = *(const half8*)&Bs[(wc * 64 + j * 16 + fr) * BK + fk];
#pragma unroll
      for (int i = 0; i < 4; ++i)
#pragma unroll
        for (int j = 0; j < 4; ++j)
          acc[i][j] = __builtin_amdgcn_mfma_f32_16x16x32_f16(ar[i], br[j], acc[i][j], 0, 0, 0);
    }
    __syncthreads();
  }

  // ---- epilogue: + bias (f32), store f32 ----
  // C/D layout: col = lane&15, row = (lane>>4)*4 + reg  [m89/m91 verified]
  const int fr = lane & 15;
  const int rq = (lane >> 4) << 2;
  float bv[4];
#pragma unroll
  for (int j = 0; j < 4; ++j)
    bv[j] = Bias[n0 + wc * 64 + j * 16 + fr];

#pragma unroll
  for (int i = 0; i < 4; ++i) {
    const int row0 = m0 + wr * 64 + i * 16 + rq;
#pragma unroll
    for (int j = 0; j < 4; ++j) {
      const int col = n0 + wc * 64 + j * 16 + fr;
#pragma unroll
      for (int r = 0; r < 4; ++r) {
        Out[(size_t)(row0 + r) * N_DIM + col] = acc[i][j][r] + bv[j];
      }
    }
  }
}

extern "C" void kernel_launch(void* const* d_in, const int* in_sizes, int n_in,
                              void* d_out, int out_size, void* d_ws, size_t ws_size,
                              hipStream_t stream) {
  const float* X    = (const float*)d_in[0];   // x (8192x4096), fp16 canonicalized to f32
  const float* W    = (const float*)d_in[1];   // weight (1024x4096) f32, K-contiguous
  const float* Bias = (const float*)d_in[2];   // bias (1024) f32
  const int*   Mk   = (const int*)d_in[3];     // keep-mask int32 0/1
  float* Out = (float*)d_out;                  // y (8192x1024) f32

  dim3 grid((M_DIM / BM) * (N_DIM / BN));      // 64 m-blocks * 8 n-blocks = 512
  dim3 block(256);
  fused_gelu_dropout_linear_kernel<<<grid, block, 0, stream>>>(X, W, Bias, Mk, Out);
}

// Round 4
// 403.683 us; speedup vs baseline: 1.2173x; 1.2173x over previous
//
#include <hip/hip_runtime.h>
#include <stdint.h>

typedef uint32_t u32;
typedef uint16_t u16;

static constexpr int M_DIM = 8192;
static constexpr int N_DIM = 1024;
static constexpr int K_DIM = 4096;
static constexpr int BM = 128;
static constexpr int BN = 128;
static constexpr int BK = 32;
static constexpr int K_TILES = K_DIM / BK;   // 128

static constexpr size_t H_ELEMS = (size_t)M_DIM * K_DIM;          // 33,554,432
static constexpr size_t W_ELEMS = (size_t)N_DIM * K_DIM;          // 4,194,304
static constexpr size_t H_BYTES = H_ELEMS * 2;                    // 64 MiB
static constexpr size_t W_BYTES = W_ELEMS * 2;                    // 8 MiB
static constexpr size_t WS_NEEDED = H_BYTES + W_BYTES;            // 72 MiB

typedef __attribute__((ext_vector_type(8))) _Float16 half8;  // MFMA A/B frag (4 VGPRs)
typedef __attribute__((ext_vector_type(4))) float f32x4;     // MFMA C/D frag

__device__ __forceinline__ u32 pack2(float a, float b) {
  union { _Float16 h[2]; u32 u; } p;
  p.h[0] = (_Float16)a;   // v_cvt_f16_f32, RNE
  p.h[1] = (_Float16)b;
  return p.u;
}

// GELU via Abramowitz-Stegun 7.1.26 erf (|err| <= 1.5e-7) + dropout keep-mask * 1/(1-0.1).
__device__ __forceinline__ float gelu_drop(float x, u32 keep) {
  float ax = fabsf(x);
  float z  = ax * 0.70710678f;
  float t  = __builtin_amdgcn_rcpf(fmaf(0.3275911f, z, 1.0f));
  float poly = fmaf(fmaf(fmaf(fmaf(1.061405429f, t, -1.453152027f),
                              t, 1.421413741f),
                         t, -0.284496736f),
                    t, 0.254829592f) * t;
  float e   = exp2f(z * z * -1.44269504f);    // exp(-z^2)
  float erf = fmaf(-poly, e, 1.0f);           // erf(|x|/sqrt(2)) in [0,1)
  float g   = 0.5f * x * (1.0f + copysignf(erf, x));
  return keep ? g * 1.1111112f : 0.0f;
}

__device__ __forceinline__ void async_cp16(const void* g, void* l) {
  __builtin_amdgcn_global_load_lds((__attribute__((address_space(1))) u32*)g,
                                   (__attribute__((address_space(3))) u32*)l,
                                   16, 0, 0);
}

// ---------------- pass 1: h = fp16(gelu(x)*mask*scale); w16 = fp16(w) ----------------
static constexpr int HB = (int)(H_ELEMS / 8 / 256);   // 16384 blocks for h
static constexpr int WB = (int)(W_ELEMS / 8 / 256);   // 2048 blocks for w

__global__ __launch_bounds__(256)
void pack_kernel(const float* __restrict__ X, const int* __restrict__ Mask,
                 const float* __restrict__ W, u16* __restrict__ H, u16* __restrict__ W16) {
  if (blockIdx.x < HB) {
    size_t t = (size_t)blockIdx.x * 256 + threadIdx.x;
    const float* xp = X + t * 8;
    const int*   mp = Mask + t * 8;
    float4 x0 = *(const float4*)(xp + 0);
    float4 x1 = *(const float4*)(xp + 4);
    uint4  m0 = *(const uint4*)(mp + 0);
    uint4  m1 = *(const uint4*)(mp + 4);
    u32 o0 = pack2(gelu_drop(x0.x, m0.x), gelu_drop(x0.y, m0.y));
    u32 o1 = pack2(gelu_drop(x0.z, m0.z), gelu_drop(x0.w, m0.w));
    u32 o2 = pack2(gelu_drop(x1.x, m1.x), gelu_drop(x1.y, m1.y));
    u32 o3 = pack2(gelu_drop(x1.z, m1.z), gelu_drop(x1.w, m1.w));
    *(uint4*)(H + t * 8) = make_uint4(o0, o1, o2, o3);
  } else {
    size_t t = (size_t)(blockIdx.x - HB) * 256 + threadIdx.x;
    const float* wp = W + t * 8;
    float4 w0 = *(const float4*)(wp + 0);
    float4 w1 = *(const float4*)(wp + 4);
    u32 o0 = pack2(w0.x, w0.y);
    u32 o1 = pack2(w0.z, w0.w);
    u32 o2 = pack2(w1.x, w1.y);
    u32 o3 = pack2(w1.z, w1.w);
    *(uint4*)(W16 + t * 8) = make_uint4(o0, o1, o2, o3);
  }
}

// ---------------- pass 2: y = h @ w16^T + bias  (m97 structure) ----------------
__global__ __launch_bounds__(256, 2)
void gemm_kernel(const u16* __restrict__ H, const u16* __restrict__ W16,
                 const float* __restrict__ Bias, float* __restrict__ Out) {
  // global_load_lds destinations: LDS slot = tid*16B, contiguous in lane order (NO padding).
  __shared__ __attribute__((aligned(16))) _Float16 As[BM * BK];  // 8 KiB
  __shared__ __attribute__((aligned(16))) _Float16 Bs[BN * BK];  // 8 KiB

  const int tid  = threadIdx.x;
  const int lane = tid & 63;
  const int wv   = tid >> 6;
  const int wr   = wv >> 1;   // wave row 0..1
  const int wc   = wv & 1;    // wave col 0..1

  // m-fast order: the 8 n-blocks of one row-stripe differ by 64 in blockIdx -> same XCD (%8),
  // so h re-reads hit that XCD's L2.
  const int bm = blockIdx.x & 63;
  const int bn = blockIdx.x >> 6;
  const int m0 = bm * BM;
  const int n0 = bn * BN;

  // staging: thread t covers (row = t>>2, 16B-chunk = t&3), t in {tid, tid+256}
  const u16* ap0 = H   + (size_t)(m0 +      (tid >> 2)) * K_DIM + ((tid & 3) << 3);
  const u16* ap1 = H   + (size_t)(m0 + 64 + (tid >> 2)) * K_DIM + ((tid & 3) << 3);
  const u16* bp0 = W16 + (size_t)(n0 +      (tid >> 2)) * K_DIM + ((tid & 3) << 3);
  const u16* bp1 = W16 + (size_t)(n0 + 64 + (tid >> 2)) * K_DIM + ((tid & 3) << 3);
  _Float16* al0 = &As[tid * 8];
  _Float16* al1 = &As[(tid + 256) * 8];
  _Float16* bl0 = &Bs[tid * 8];
  _Float16* bl1 = &Bs[(tid + 256) * 8];

  f32x4 acc[4][4];
#pragma unroll
  for (int i = 0; i < 4; ++i)
#pragma unroll
    for (int j = 0; j < 4; ++j)
      acc[i][j] = (f32x4){0.f, 0.f, 0.f, 0.f};

  const int fr = lane & 15;
  const int fk = (lane >> 4) << 3;   // k-chunk 0/8/16/24

#pragma unroll 1
  for (int kt = 0; kt < K_TILES; ++kt) {
    async_cp16(ap0, al0);
    async_cp16(ap1, al1);
    async_cp16(bp0, bl0);
    async_cp16(bp1, bl1);
    ap0 += BK; ap1 += BK; bp0 += BK; bp1 += BK;
    __syncthreads();   // drains vmcnt (global_load_lds) per barrier semantics

    half8 ar[4], br[4];
#pragma unroll
    for (int i = 0; i < 4; ++i)
      ar[i] = *(const half8*)&As[(wr * 64 + i * 16 + fr) * BK + fk];
#pragma unroll
    for (int j = 0; j < 4; ++j)
      br[j] = *(const half8*)&Bs[(wc * 64 + j * 16 + fr) * BK + fk];
#pragma unroll
    for (int i = 0; i < 4; ++i)
#pragma unroll
      for (int j = 0; j < 4; ++j)
        acc[i][j] = __builtin_amdgcn_mfma_f32_16x16x32_f16(ar[i], br[j], acc[i][j], 0, 0, 0);
    __syncthreads();
  }

  // epilogue: C/D layout col = lane&15, row = (lane>>4)*4 + reg  [verified R3]
  const int rq = (lane >> 4) << 2;
  float bv[4];
#pragma unroll
  for (int j = 0; j < 4; ++j)
    bv[j] = Bias[n0 + wc * 64 + j * 16 + fr];

#pragma unroll
  for (int i = 0; i < 4; ++i) {
    const int row0 = m0 + wr * 64 + i * 16 + rq;
#pragma unroll
    for (int j = 0; j < 4; ++j) {
      const int col = n0 + wc * 64 + j * 16 + fr;
#pragma unroll
      for (int r = 0; r < 4; ++r) {
        Out[(size_t)(row0 + r) * N_DIM + col] = acc[i][j][r] + bv[j];
      }
    }
  }
}

// ---------------- fallback: verified R3 fused kernel (used only if ws too small) ----------------
static constexpr int A_STRIDE = 40;

__global__ __launch_bounds__(256, 2)
void fused_fallback_kernel(const float* __restrict__ X, const float* __restrict__ W,
                           const float* __restrict__ Bias, const int* __restrict__ Mask,
                           float* __restrict__ Out) {
  __shared__ __attribute__((aligned(16))) _Float16 As[BM * A_STRIDE];
  __shared__ __attribute__((aligned(16))) _Float16 Bs[BN * BK];

  const int tid  = threadIdx.x;
  const int lane = tid & 63;
  const int wv   = tid >> 6;
  const int wr   = wv >> 1;
  const int wc   = wv & 1;
  const int bm = blockIdx.x & 63;
  const int bn = blockIdx.x >> 6;
  const int m0 = bm * BM;
  const int n0 = bn * BN;

  const int a_m = tid >> 1;
  const int a_k = (tid & 1) << 4;
  const float* xptr = X    + (size_t)(m0 + a_m) * K_DIM + a_k;
  const int*   mptr = Mask + (size_t)(m0 + a_m) * K_DIM + a_k;
  _Float16* a_lds = &As[a_m * A_STRIDE + a_k];

  const int i0 = tid, i1 = tid + 256;
  const float* wp0 = W + (size_t)(n0 + (i0 >> 2)) * K_DIM + ((i0 & 3) << 3);
  const float* wp1 = W + (size_t)(n0 + (i1 >> 2)) * K_DIM + ((i1 & 3) << 3);
  _Float16* bl0 = &Bs[i0 * 8];
  _Float16* bl1 = &Bs[i1 * 8];

  f32x4 acc[4][4];
#pragma unroll
  for (int i = 0; i < 4; ++i)
#pragma unroll
    for (int j = 0; j < 4; ++j)
      acc[i][j] = (f32x4){0.f, 0.f, 0.f, 0.f};

  float4 xf0 = *(const float4*)(xptr +  0);
  float4 xf1 = *(const float4*)(xptr +  4);
  float4 xf2 = *(const float4*)(xptr +  8);
  float4 xf3 = *(const float4*)(xptr + 12);
  uint4  mr0 = *(const uint4*)(mptr +  0);
  uint4  mr1 = *(const uint4*)(mptr +  4);
  uint4  mr2 = *(const uint4*)(mptr +  8);
  uint4  mr3 = *(const uint4*)(mptr + 12);
  float4 wf0 = *(const float4*)(wp0 + 0);
  float4 wf1 = *(const float4*)(wp0 + 4);
  float4 wf2 = *(const float4*)(wp1 + 0);
  float4 wf3 = *(const float4*)(wp1 + 4);

#pragma unroll 1
  for (int kt = 0; kt < K_TILES; ++kt) {
    {
      float xs[16] = {xf0.x, xf0.y, xf0.z, xf0.w, xf1.x, xf1.y, xf1.z, xf1.w,
                      xf2.x, xf2.y, xf2.z, xf2.w, xf3.x, xf3.y, xf3.z, xf3.w};
      u32 mk[16]   = {mr0.x, mr0.y, mr0.z, mr0.w, mr1.x, mr1.y, mr1.z, mr1.w,
                      mr2.x, mr2.y, mr2.z, mr2.w, mr3.x, mr3.y, mr3.z, mr3.w};
      u32 ow[8];
#pragma unroll
      for (int e = 0; e < 8; ++e)
        ow[e] = pack2(gelu_drop(xs[2 * e], mk[2 * e]), gelu_drop(xs[2 * e + 1], mk[2 * e + 1]));
      ((uint4*)a_lds)[0] = make_uint4(ow[0], ow[1], ow[2], ow[3]);
      ((uint4*)a_lds)[1] = make_uint4(ow[4], ow[5], ow[6], ow[7]);
    }
    {
      *(uint4*)bl0 = make_uint4(pack2(wf0.x, wf0.y), pack2(wf0.z, wf0.w),
                                pack2(wf1.x, wf1.y), pack2(wf1.z, wf1.w));
      *(uint4*)bl1 = make_uint4(pack2(wf2.x, wf2.y), pack2(wf2.z, wf2.w),
                                pack2(wf3.x, wf3.y), pack2(wf3.z, wf3.w));
    }
    __syncthreads();

    if (kt + 1 < K_TILES) {
      xptr += BK; mptr += BK; wp0 += BK; wp1 += BK;
      xf0 = *(const float4*)(xptr +  0);
      xf1 = *(const float4*)(xptr +  4);
      xf2 = *(const float4*)(xptr +  8);
      xf3 = *(const float4*)(xptr + 12);
      mr0 = *(const uint4*)(mptr +  0);
      mr1 = *(const uint4*)(mptr +  4);
      mr2 = *(const uint4*)(mptr +  8);
      mr3 = *(const uint4*)(mptr + 12);
      wf0 = *(const float4*)(wp0 + 0);
      wf1 = *(const float4*)(wp0 + 4);
      wf2 = *(const float4*)(wp1 + 0);
      wf3 = *(const float4*)(wp1 + 4);
    }

    {
      const int fr2 = lane & 15;
      const int fk2 = (lane >> 4) << 3;
      half8 ar[4], br[4];
#pragma unroll
      for (int i = 0; i < 4; ++i)
        ar[i] = *(const half8*)&As[(wr * 64 + i * 16 + fr2) * A_STRIDE + fk2];
#pragma unroll
      for (int j = 0; j < 4; ++j)
        br[j] = *(const half8*)&Bs[(wc * 64 + j * 16 + fr2) * BK + fk2];
#pragma unroll
      for (int i = 0; i < 4; ++i)
#pragma unroll
        for (int j = 0; j < 4; ++j)
          acc[i][j] = __builtin_amdgcn_mfma_f32_16x16x32_f16(ar[i], br[j], acc[i][j], 0, 0, 0);
    }
    __syncthreads();
  }

  const int fr = lane & 15;
  const int rq = (lane >> 4) << 2;
  float bv[4];
#pragma unroll
  for (int j = 0; j < 4; ++j)
    bv[j] = Bias[n0 + wc * 64 + j * 16 + fr];
#pragma unroll
  for (int i = 0; i < 4; ++i) {
    const int row0 = m0 + wr * 64 + i * 16 + rq;
#pragma unroll
    for (int j = 0; j < 4; ++j) {
      const int col = n0 + wc * 64 + j * 16 + fr;
#pragma unroll
      for (int r = 0; r < 4; ++r)
        Out[(size_t)(row0 + r) * N_DIM + col] = acc[i][j][r] + bv[j];
    }
  }
}

extern "C" void kernel_launch(void* const* d_in, const int* in_sizes, int n_in,
                              void* d_out, int out_size, void* d_ws, size_t ws_size,
                              hipStream_t stream) {
  const float* X    = (const float*)d_in[0];   // x (8192x4096), fp16 canonicalized to f32
  const float* W    = (const float*)d_in[1];   // weight (1024x4096) f32, K-contiguous
  const float* Bias = (const float*)d_in[2];   // bias (1024) f32
  const int*   Mk   = (const int*)d_in[3];     // keep-mask int32 0/1
  float* Out = (float*)d_out;                  // y (8192x1024) f32

  if (ws_size >= WS_NEEDED) {
    u16* H   = (u16*)d_ws;
    u16* W16 = (u16*)((char*)d_ws + H_BYTES);
    pack_kernel<<<HB + WB, 256, 0, stream>>>(X, Mk, W, H, W16);
    gemm_kernel<<<(M_DIM / BM) * (N_DIM / BN), 256, 0, stream>>>(H, W16, Bias, Out);
  } else {
    fused_fallback_kernel<<<(M_DIM / BM) * (N_DIM / BN), 256, 0, stream>>>(X, W, Bias, Mk, Out);
  }
}